// Round 5
// baseline (567.774 us; speedup 1.0000x reference)
//
#include <hip/hip_runtime.h>
#include <math.h>

// SincNetLayer1D on MI355X — round 5.
// B=128, L=2048, F=64, fsize=129, fs=16000. fp32 VALU-bound (no fp32 MFMA).
// Round-4 counters: VALUBusy 77.6%, 302us = 2.1x the 110us FMA floor ->
// inner-loop instruction bloat. This round: zero-padded input (no bounds
// logic), multiplicative Gaussian recurrence (no per-step exp), imm-offset
// loads (no per-step address math). Target ~140-180us.

#define PI_F 3.14159265358979323846f
#define L_LEN 2048
#define F_N   64
#define FSIZE 129
#define FS_F  16000.0f
#define PADL  64
#define PADR  80
#define PROW  (PADL + L_LEN + PADR)   // 2192 float2 per padded batch row

// ---------------- prep: krki[k][f] = (kr, ki), 129*64 float2 = 66 KB ----------------
__global__ void prep_filters(const float* __restrict__ fc,
                             const float* __restrict__ fbw,
                             float2* __restrict__ krki)
{
    const int f   = blockIdx.x;    // 64 blocks
    const int tid = threadIdx.x;   // 256 threads
    __shared__ float red[256];

    const float band = fbw[f] * FS_F;
    float bp = 0.0f;
    if (tid < FSIZE) {
        float y;
        const int m = tid - 64;
        if (m == 0) {
            y = 1.0f;
        } else {
            const float tr  = (float)abs(m) / FS_F;
            const float arg = 2.0f * PI_F * band * tr;
            y = __sinf(arg) / arg;
        }
        const float nn  = (float)tid * (129.0f / 128.0f);       // linspace(0,129,129)
        const float win = 0.54f - 0.46f * __cosf(2.0f * PI_F * nn / 129.0f);
        bp = y * (2.0f * band) * win;
    }
    red[tid] = fabsf(bp);
    __syncthreads();
    for (int s = 128; s > 0; s >>= 1) {
        if (tid < s) red[tid] = fmaxf(red[tid], red[tid + s]);
        __syncthreads();
    }
    const float inv = 1.0f / (red[0] + 1e-9f);
    if (tid < FSIZE) {
        const float v  = bp * inv;
        const float ph = 2.0f * PI_F * fc[f] * ((float)tid * (129.0f / 128.0f));
        float sn, cs;
        __sincosf(ph, &sn, &cs);
        krki[tid * F_N + f] = make_float2(v * cs, v * sn);
    }
}

// ---------------- prep: zero-padded input copy ----------------
__global__ void prep_pad(const float* __restrict__ in, float2* __restrict__ pad, int B)
{
    const int idx = blockIdx.x * 256 + threadIdx.x;
    if (idx >= B * PROW) return;
    const int b = idx / PROW;
    const int i = idx - b * PROW;
    const int p = i - PADL;
    float2 v = make_float2(0.0f, 0.0f);
    if (p >= 0 && p < L_LEN) v = reinterpret_cast<const float2*>(in)[b * L_LEN + p];
    pad[idx] = v;
}

// ---------------- main conv ----------------
__global__ __launch_bounds__(256, 4)
void sinc_conv(const float2* __restrict__ pad,    // (B, PROW)
               const float2* __restrict__ krki,   // (129, 64)
               const float* __restrict__ tl,
               const float* __restrict__ st,
               float* __restrict__ out)           // (B, L, 128)
{
    const int tid = threadIdx.x;
    const int wv  = tid >> 6;
    const int f   = tid & 63;
    const int nlb = L_LEN / 64;                       // 32 l-blocks per batch
    const int b   = blockIdx.x / nlb;
    const int lw  = (blockIdx.x % nlb) * 64 + wv * 16;

    // Gaussian mask: m(p) = exp(-(p-c)^2/(2 s^2)) * minv, via multiplicative
    // recurrence m *= u; u *= d  (d = exp(-1/s^2), exact telescoping).
    const float tlv = tl[f];
    const float stv = st[f];
    const float c_f = (stv + tlv) * 0.5f;
    const float sd  = tlv * (1.0f / 1.665f) + 1e-9f;
    const float rs  = 1.0f / sd;
    const float i2  = 0.5f * rs * rs;                 // 1/(2 s^2)
    const float zn  = (floorf(c_f + 0.5f) - c_f) * rs;
    const float minv = 1.0f / (__expf(-0.5f * zn * zn) + 1e-9f);

    const float p0 = (float)(lw - 64);                // first window position
    float m = __expf(-(p0 - c_f) * (p0 - c_f) * i2) * minv;
    float u = __expf((2.0f * (c_f - p0) - 1.0f) * i2);
    const float d = __expf(-2.0f * i2);

    const float2* xb = pad + (size_t)b * PROW + (PADL + lw - 64);
    const float2* tb = krki + f;

    // ring: slot (position mod 16); lw % 16 == 0 so init position lw-64+j -> slot j
    float2 w[16];
    float  ar[16], ai[16];
#pragma unroll
    for (int j = 0; j < 16; ++j) {
        const float2 xv = xb[j];
        w[j] = make_float2(xv.x * m, xv.y * m);
        m *= u; u *= d;
        ar[j] = 0.0f; ai[j] = 0.0f;
    }

    const float2* xs = xb + 16;        // xs[k] = position lw-48+k (pad-safe for k<128)
    float2 tv = tb[0];                 // tap k=0

#pragma unroll 1
    for (int k0 = 0; k0 < 8; ++k0) {
        const float2* xk = xs + (k0 << 4);
        const float2* tk = tb + (size_t)((k0 << 4) + 1) * F_N;   // taps k+1
#pragma unroll
        for (int kk = 0; kk < 16; ++kk) {
            const float2 tnx = tk[(size_t)kk * F_N];   // tap[k+1], imm-ish offset
            const float2 xnx = xk[kk];                 // new window element
#pragma unroll
            for (int j = 0; j < 16; ++j) {
                const int s = (kk + j) & 15;           // static after unroll
                ar[j] = fmaf(w[s].x,  tv.x, ar[j]);
                ar[j] = fmaf(w[s].y, -tv.y, ar[j]);
                ai[j] = fmaf(w[s].x,  tv.y, ai[j]);
                ai[j] = fmaf(w[s].y,  tv.x, ai[j]);
            }
            w[kk] = make_float2(xnx.x * m, xnx.y * m); // slot k&15 == kk
            m *= u; u *= d;
            tv = tnx;
        }
    }
    // final tap k = 128: slots (128+j)&15 == j, tv == tap[128]
#pragma unroll
    for (int j = 0; j < 16; ++j) {
        ar[j] = fmaf(w[j].x,  tv.x, ar[j]);
        ar[j] = fmaf(w[j].y, -tv.y, ar[j]);
        ai[j] = fmaf(w[j].x,  tv.y, ai[j]);
        ai[j] = fmaf(w[j].y,  tv.x, ai[j]);
    }

    float* ob = out + ((size_t)b * L_LEN + lw) * (2 * F_N);
#pragma unroll
    for (int j = 0; j < 16; ++j) {
        ob[j * (2 * F_N) + f]       = ar[j];   // real: channels 0..63
        ob[j * (2 * F_N) + F_N + f] = ai[j];   // imag: channels 64..127
    }
}

extern "C" void kernel_launch(void* const* d_in, const int* in_sizes, int n_in,
                              void* d_out, int out_size, void* d_ws, size_t ws_size,
                              hipStream_t stream)
{
    const float* in  = (const float*)d_in[0];   // (B, 2048, 2) fp32
    const float* fc  = (const float*)d_in[1];
    const float* fbw = (const float*)d_in[2];
    const float* tl  = (const float*)d_in[3];
    const float* st  = (const float*)d_in[4];

    const int B = in_sizes[0] / (L_LEN * 2);    // 128

    float2* krki = (float2*)d_ws;                         // 66,048 B
    float2* pad  = (float2*)((char*)d_ws + 66048);        // B*PROW*8 = 2,244,608 B

    prep_filters<<<F_N, 256, 0, stream>>>(fc, fbw, krki);
    prep_pad<<<(B * PROW + 255) / 256, 256, 0, stream>>>(in, pad, B);
    sinc_conv<<<B * (L_LEN / 64), 256, 0, stream>>>(pad, krki, tl, st, (float*)d_out);
}

// Round 6
// 362.907 us; speedup vs baseline: 1.5645x; 1.5645x over previous
//
#include <hip/hip_runtime.h>
#include <math.h>

// SincNetLayer1D on MI355X — round 6.
// Round-5 lesson: __launch_bounds__(256,4) capped VGPR at 64 < live state
// (~85) -> inner-loop scratch spills (FETCH 568MB, WRITE 1.5GB, VALUBusy 34%).
// This round: identical algorithm, launch_bounds back to (256,3).
// Per-step cost: 64 FMA + 2 recurrence muls + 2 mask muls + ~2 moves.

#define PI_F 3.14159265358979323846f
#define L_LEN 2048
#define F_N   64
#define FSIZE 129
#define FS_F  16000.0f
#define PADL  64
#define PADR  80
#define PROW  (PADL + L_LEN + PADR)   // 2192 float2 per padded batch row

// ---------------- prep: krki[k][f] = (kr, ki), 129*64 float2 = 66 KB ----------------
__global__ void prep_filters(const float* __restrict__ fc,
                             const float* __restrict__ fbw,
                             float2* __restrict__ krki)
{
    const int f   = blockIdx.x;    // 64 blocks
    const int tid = threadIdx.x;   // 256 threads
    __shared__ float red[256];

    const float band = fbw[f] * FS_F;
    float bp = 0.0f;
    if (tid < FSIZE) {
        float y;
        const int m = tid - 64;
        if (m == 0) {
            y = 1.0f;
        } else {
            const float tr  = (float)abs(m) / FS_F;
            const float arg = 2.0f * PI_F * band * tr;
            y = __sinf(arg) / arg;
        }
        const float nn  = (float)tid * (129.0f / 128.0f);       // linspace(0,129,129)
        const float win = 0.54f - 0.46f * __cosf(2.0f * PI_F * nn / 129.0f);
        bp = y * (2.0f * band) * win;
    }
    red[tid] = fabsf(bp);
    __syncthreads();
    for (int s = 128; s > 0; s >>= 1) {
        if (tid < s) red[tid] = fmaxf(red[tid], red[tid + s]);
        __syncthreads();
    }
    const float inv = 1.0f / (red[0] + 1e-9f);
    if (tid < FSIZE) {
        const float v  = bp * inv;
        const float ph = 2.0f * PI_F * fc[f] * ((float)tid * (129.0f / 128.0f));
        float sn, cs;
        __sincosf(ph, &sn, &cs);
        krki[tid * F_N + f] = make_float2(v * cs, v * sn);
    }
}

// ---------------- prep: zero-padded input copy ----------------
__global__ void prep_pad(const float* __restrict__ in, float2* __restrict__ pad, int B)
{
    const int idx = blockIdx.x * 256 + threadIdx.x;
    if (idx >= B * PROW) return;
    const int b = idx / PROW;
    const int i = idx - b * PROW;
    const int p = i - PADL;
    float2 v = make_float2(0.0f, 0.0f);
    if (p >= 0 && p < L_LEN) v = reinterpret_cast<const float2*>(in)[b * L_LEN + p];
    pad[idx] = v;
}

// ---------------- main conv ----------------
__global__ __launch_bounds__(256, 3)   // 3 waves/EU -> VGPR cap ~170; live state ~85. DO NOT raise to 4: spills (round 5).
void sinc_conv(const float2* __restrict__ pad,    // (B, PROW)
               const float2* __restrict__ krki,   // (129, 64)
               const float* __restrict__ tl,
               const float* __restrict__ st,
               float* __restrict__ out)           // (B, L, 128)
{
    const int tid = threadIdx.x;
    const int wv  = tid >> 6;
    const int f   = tid & 63;
    const int nlb = L_LEN / 64;                       // 32 l-blocks per batch
    const int b   = blockIdx.x / nlb;
    const int lw  = (blockIdx.x % nlb) * 64 + wv * 16;

    // Gaussian mask: m(p) = exp(-(p-c)^2/(2 s^2)) * minv, via multiplicative
    // recurrence m *= u; u *= d  (d = exp(-1/s^2), exact telescoping).
    const float tlv = tl[f];
    const float stv = st[f];
    const float c_f = (stv + tlv) * 0.5f;
    const float sd  = tlv * (1.0f / 1.665f) + 1e-9f;
    const float rs  = 1.0f / sd;
    const float i2  = 0.5f * rs * rs;                 // 1/(2 s^2)
    const float zn  = (floorf(c_f + 0.5f) - c_f) * rs;
    const float minv = 1.0f / (__expf(-0.5f * zn * zn) + 1e-9f);

    const float p0 = (float)(lw - 64);                // first window position
    float m = __expf(-(p0 - c_f) * (p0 - c_f) * i2) * minv;
    float u = __expf((2.0f * (c_f - p0) - 1.0f) * i2);
    const float d = __expf(-2.0f * i2);

    const float2* xb = pad + (size_t)b * PROW + (PADL + lw - 64);
    const float2* tb = krki + f;

    // ring: slot (position mod 16); lw % 16 == 0 so init position lw-64+j -> slot j
    float2 w[16];
    float  ar[16], ai[16];
#pragma unroll
    for (int j = 0; j < 16; ++j) {
        const float2 xv = xb[j];
        w[j] = make_float2(xv.x * m, xv.y * m);
        m *= u; u *= d;
        ar[j] = 0.0f; ai[j] = 0.0f;
    }

    const float2* xs = xb + 16;        // xs[k] = position lw-48+k (pad-safe for k<128)
    float2 tv = tb[0];                 // tap k=0

#pragma unroll 1
    for (int k0 = 0; k0 < 8; ++k0) {
        const float2* xk = xs + (k0 << 4);
        const float2* tk = tb + (size_t)((k0 << 4) + 1) * F_N;   // taps k+1
#pragma unroll
        for (int kk = 0; kk < 16; ++kk) {
            const float2 tnx = tk[(size_t)kk * F_N];   // tap[k+1]
            const float2 xnx = xk[kk];                 // new window element
#pragma unroll
            for (int j = 0; j < 16; ++j) {
                const int s = (kk + j) & 15;           // static after unroll
                ar[j] = fmaf(w[s].x,  tv.x, ar[j]);
                ar[j] = fmaf(w[s].y, -tv.y, ar[j]);
                ai[j] = fmaf(w[s].x,  tv.y, ai[j]);
                ai[j] = fmaf(w[s].y,  tv.x, ai[j]);
            }
            w[kk] = make_float2(xnx.x * m, xnx.y * m); // slot k&15 == kk
            m *= u; u *= d;
            tv = tnx;
        }
    }
    // final tap k = 128: slots (128+j)&15 == j, tv == tap[128]
#pragma unroll
    for (int j = 0; j < 16; ++j) {
        ar[j] = fmaf(w[j].x,  tv.x, ar[j]);
        ar[j] = fmaf(w[j].y, -tv.y, ar[j]);
        ai[j] = fmaf(w[j].x,  tv.y, ai[j]);
        ai[j] = fmaf(w[j].y,  tv.x, ai[j]);
    }

    float* ob = out + ((size_t)b * L_LEN + lw) * (2 * F_N);
#pragma unroll
    for (int j = 0; j < 16; ++j) {
        ob[j * (2 * F_N) + f]       = ar[j];   // real: channels 0..63
        ob[j * (2 * F_N) + F_N + f] = ai[j];   // imag: channels 64..127
    }
}

extern "C" void kernel_launch(void* const* d_in, const int* in_sizes, int n_in,
                              void* d_out, int out_size, void* d_ws, size_t ws_size,
                              hipStream_t stream)
{
    const float* in  = (const float*)d_in[0];   // (B, 2048, 2) fp32
    const float* fc  = (const float*)d_in[1];
    const float* fbw = (const float*)d_in[2];
    const float* tl  = (const float*)d_in[3];
    const float* st  = (const float*)d_in[4];

    const int B = in_sizes[0] / (L_LEN * 2);    // 128

    float2* krki = (float2*)d_ws;                         // 66,048 B
    float2* pad  = (float2*)((char*)d_ws + 66048);        // B*PROW*8 = 2,244,608 B

    prep_filters<<<F_N, 256, 0, stream>>>(fc, fbw, krki);
    prep_pad<<<(B * PROW + 255) / 256, 256, 0, stream>>>(in, pad, B);
    sinc_conv<<<B * (L_LEN / 64), 256, 0, stream>>>(pad, krki, tl, st, (float*)d_out);
}